// Round 8
// baseline (214.454 us; speedup 1.0000x reference)
//
#include <hip/hip_runtime.h>
#include <cstdint>
#include <cstddef>

constexpr int kN = 2048;   // layer size
constexpr int kB = 4096;   // batch
constexpr int kR = 4;      // displacement rank

typedef __attribute__((ext_vector_type(4))) float f32x4;
typedef __attribute__((ext_vector_type(8))) short short8;
typedef __attribute__((ext_vector_type(8))) unsigned short ushort8;

__device__ __forceinline__ unsigned short f2bf(float f) {
  unsigned u = __float_as_uint(f);
  u += 0x7FFFu + ((u >> 16) & 1u);
  return (unsigned short)(u >> 16);
}

__device__ __forceinline__ void gload_lds16(const void* g, void* l) {
  __builtin_amdgcn_global_load_lds(
      (const __attribute__((address_space(1))) void*)g,
      (__attribute__((address_space(3))) void*)l, 16, 0, 0);
}

// ---------------- kernel 1 (fused): cast x->bf16 + per-diagonal prefix scan ----------------
__global__ void prep_kernel(const float* __restrict__ x,
                            const float* __restrict__ G,
                            const float* __restrict__ H,
                            unsigned short* __restrict__ xb,
                            unsigned short* __restrict__ Dp) {
  __shared__ float wsum[4];
  const int tid = threadIdx.x;

  if (blockIdx.x < (kB * kN) / (256 * 8)) {
    const int t = blockIdx.x * 256 + tid;
    const float4* xv = (const float4*)x;
    float4 a = xv[t * 2];
    float4 b = xv[t * 2 + 1];
    ushort8 o;
    o[0] = f2bf(a.x); o[1] = f2bf(a.y); o[2] = f2bf(a.z); o[3] = f2bf(a.w);
    o[4] = f2bf(b.x); o[5] = f2bf(b.y); o[6] = f2bf(b.z); o[7] = f2bf(b.w);
    *(ushort8*)(xb + (size_t)t * 8) = o;
    return;
  }

  const int d = blockIdx.x - (kB * kN) / (256 * 8);
  const int lane = tid & 63, wave = tid >> 6;
  const int v0 = tid * 8;

  float loc[8];
  float run = 0.f;
#pragma unroll
  for (int jj = 0; jj < 8; ++jj) {
    const int v = v0 + jj;
    float q = 0.f;
#pragma unroll
    for (int t = 0; t < kR; ++t)
      q += G[t * kN + ((v + d) & (kN - 1))] * H[t * kN + v];
    run += q;
    loc[jj] = run;
  }

  float incl = run;
#pragma unroll
  for (int off = 1; off < 64; off <<= 1) {
    float tv = __shfl_up(incl, off, 64);
    if (lane >= off) incl += tv;
  }
  if (lane == 63) wsum[wave] = incl;
  __syncthreads();
  float woff = 0.f, total = 0.f;
#pragma unroll
  for (int w = 0; w < 4; ++w) {
    const float s = wsum[w];
    total += s;
    if (w < wave) woff += s;
  }
  const float exc = woff + incl - run;

  ushort8 o;
#pragma unroll
  for (int jj = 0; jj < 8; ++jj)
    o[jj] = f2bf(2.f * (exc + loc[jj]) - total);
  *(ushort8*)(Dp + (size_t)d * kN + v0) = o;
}

// ---------------- kernel 2: diagonal -> row-major transpose ----------------
__global__ void build_M_kernel(const unsigned short* __restrict__ Dp,
                               unsigned short* __restrict__ Mb) {
  __shared__ unsigned short lds[128][64];
  const int tid = threadIdx.x;
  const int i0 = blockIdx.y * 64, j0 = blockIdx.x * 64;
  const int delta0 = (i0 - j0 - 63) & (kN - 1);
#pragma unroll
  for (int it = 0; it < 32; ++it) {
    const int lin = it * 256 + tid;
    const int dd = lin >> 6, jj = lin & 63;
    lds[dd][jj] = Dp[(size_t)((delta0 + dd) & (kN - 1)) * kN + j0 + jj];
  }
  __syncthreads();
#pragma unroll
  for (int it = 0; it < 16; ++it) {
    const int lin = it * 256 + tid;
    const int ii = lin >> 6, jj = lin & 63;
    Mb[(size_t)(i0 + ii) * kN + j0 + jj] = lds[ii - jj + 63][jj];
  }
}

// ---------------- kernel 2b: zero the f32 output (poisoned 0xAA by harness) ----------------
__global__ void zero_out_kernel(float4* __restrict__ out4) {
  const int i = blockIdx.x * blockDim.x + threadIdx.x;
  out4[i * 2]     = float4{0.f, 0.f, 0.f, 0.f};
  out4[i * 2 + 1] = float4{0.f, 0.f, 0.f, 0.f};
}

// ---------------- kernel 3: out += x @ M^T  (8-phase, split-K=2) ----------------
// BM=BN=256, BK=64, 512 thr (8 waves, per-wave 64x32 per quadrant).
// Phase = {vmcnt(N) -> s_barrier -> 12 ds_read_b128 -> 1 half-stage (2 gload_lds)
//          -> lgkmcnt(0) -> 16 MFMA}. READS STRICTLY AFTER THE FENCE (R7 bug fix).
// FIFO ledger (loads, prologue=12 in flight): steady PH0:vm(8) PH1:vm(6)
// PH4:vm(8) PH5:vm(6), others free; tail PH4:vm(4) PH5:vm(0). WAR: every stage
// targets a buffer whose last reader's lgkmcnt(0) precedes the head barrier
// the stage is issued behind; no phase stages a buffer it reads.
// LDS 128 KB: As/Bs[2 parity][2 half][128x64]. Grid 8x16x2 = 256 blocks = 1/CU.
__global__ __launch_bounds__(512, 2) void gemm_kernel(
    const unsigned short* __restrict__ A,
    const unsigned short* __restrict__ Bt,
    float* __restrict__ C) {
  __shared__ unsigned short As[2][2][128 * 64];   // 64 KB
  __shared__ unsigned short Bs[2][2][128 * 64];   // 64 KB

  const int tid = threadIdx.x;
  const int lane = tid & 63, wave = tid >> 6;
  const int r16 = lane & 15, kg = lane >> 4;
  const int mrow0 = (wave >> 2) * 64;    // wave sub-rows within a 128-row half
  const int ncol0 = (wave & 3) * 32;     // wave sub-cols within a 128-col half

  const int row0 = blockIdx.y * 256;
  const int col0 = blockIdx.x * 256;
  const int kz = blockIdx.z;             // split-K slice (K/2 = 1024 each)

  const char* Abase = (const char*)(A + (size_t)row0 * kN + kz * 1024);
  const char* Bbase = (const char*)(Bt + (size_t)col0 * kN + kz * 1024);

  // staging: per thread 2 chunks; row = i*64+(tid>>3), chunk = tid&7.
  // chunk pre-swizzled with (row&7) involution (rule #21); same XOR on reads.
  int goff[2];
#pragma unroll
  for (int i = 0; i < 2; ++i) {
    const int r = i * 64 + (tid >> 3), c = tid & 7;
    goff[i] = r * (kN * 2) + ((c ^ (r & 7)) << 4);
  }

  f32x4 acc[4][4][2] = {};   // [quadrant][mf][nf]

#define STG(MAT, BUF, H, KT)                                                   \
  { _Pragma("unroll")                                                          \
    for (int i = 0; i < 2; ++i)                                                \
      gload_lds16(MAT##base + (H) * 128 * (kN * 2) + (KT) * 128 + goff[i],     \
                  (char*)&MAT##s[BUF][H][0] + (i * 512 + tid) * 16); }

#define PH(BUF, QM, QN, Q, STGCODE, WTCODE)                                    \
  {                                                                            \
    WTCODE;                                  /* vmcnt for THIS phase's data */ \
    __builtin_amdgcn_s_barrier();            /* all waves' stages landed   */  \
    const char* ab = (const char*)&As[BUF][QM][0];                             \
    const char* bb = (const char*)&Bs[BUF][QN][0];                             \
    short8 a_[2][4], b_[2][2];                                                 \
    _Pragma("unroll")                                                          \
    for (int ks = 0; ks < 2; ++ks) {                                           \
      _Pragma("unroll")                                                        \
      for (int mf = 0; mf < 4; ++mf) {                                         \
        const int row = mrow0 + mf * 16 + r16;                                 \
        a_[ks][mf] = *(const short8*)(ab + row * 128 +                         \
                                      (((ks * 4 + kg) ^ (row & 7)) << 4));     \
      }                                                                        \
      _Pragma("unroll")                                                        \
      for (int nf = 0; nf < 2; ++nf) {                                         \
        const int row = ncol0 + nf * 16 + r16;                                 \
        b_[ks][nf] = *(const short8*)(bb + row * 128 +                         \
                                      (((ks * 4 + kg) ^ (row & 7)) << 4));     \
      }                                                                        \
    }                                                                          \
    STGCODE;                                 /* issue prefetch stage */        \
    asm volatile("s_waitcnt lgkmcnt(0)" ::: "memory");                         \
    __builtin_amdgcn_sched_barrier(0);                                         \
    __builtin_amdgcn_s_setprio(1);                                             \
    _Pragma("unroll")                                                          \
    for (int ks = 0; ks < 2; ++ks)                                             \
      _Pragma("unroll")                                                        \
      for (int mf = 0; mf < 4; ++mf)                                           \
        _Pragma("unroll")                                                      \
        for (int nf = 0; nf < 2; ++nf)                                         \
          acc[Q][mf][nf] = __builtin_amdgcn_mfma_f32_16x16x32_bf16(            \
              a_[ks][mf], b_[ks][nf], acc[Q][mf][nf], 0, 0, 0);                \
    __builtin_amdgcn_s_setprio(0);                                             \
  }

#define VM(N) asm volatile("s_waitcnt vmcnt(" #N ")" ::: "memory")

  // prologue: 6 half-stages = 12 loads in flight
  STG(A, 0, 0, 0);   // pair 1: A0(t0)
  STG(B, 0, 0, 0);   // pair 2: B0(t0)
  STG(A, 0, 1, 0);   // pair 3: A1(t0)
  STG(B, 0, 1, 0);   // pair 4: B1(t0)
  STG(A, 1, 0, 1);   // pair 5: A0(t1)
  STG(B, 1, 0, 1);   // pair 6: B0(t1)

  const int NIT = 1024 / 128;   // 8 iterations x 2 K-tiles of 64
  for (int it = 0; it < NIT; ++it) {
    const int t1 = 2 * it + 1, t2 = 2 * it + 2, t3 = 2 * it + 3;
    const bool more = (it + 1) < NIT;

    PH(0, 0, 0, 0, STG(A, 1, 1, t1), VM(8));
    PH(0, 0, 1, 1, STG(B, 1, 1, t1), VM(6));
    PH(0, 1, 0, 2, if (more) STG(A, 0, 0, t2), );
    PH(0, 1, 1, 3, if (more) STG(B, 0, 0, t2), );
    PH(1, 0, 0, 0, if (more) STG(A, 0, 1, t2), if (more) VM(8); else VM(4));
    PH(1, 0, 1, 1, if (more) STG(B, 0, 1, t2), if (more) VM(6); else VM(0));
    PH(1, 1, 0, 2, if (more) STG(A, 1, 0, t3), );
    PH(1, 1, 1, 3, if (more) STG(B, 1, 0, t3), );
  }
#undef PH
#undef STG
#undef VM

  // epilogue: split-K partial -> atomicAdd into zeroed C.
  // D layout: row = (lane>>4)*4 + reg, col = lane&15 (verified)
#pragma unroll
  for (int q = 0; q < 4; ++q) {
    const int qm = q >> 1, qn = q & 1;
#pragma unroll
    for (int mf = 0; mf < 4; ++mf)
#pragma unroll
      for (int nf = 0; nf < 2; ++nf) {
        const int r = row0 + qm * 128 + mrow0 + mf * 16 + kg * 4;
        const int c = col0 + qn * 128 + ncol0 + nf * 16 + r16;
#pragma unroll
        for (int j = 0; j < 4; ++j)
          atomicAdd(&C[(size_t)(r + j) * kN + c], acc[q][mf][nf][j]);
      }
  }
}

extern "C" void kernel_launch(void* const* d_in, const int* in_sizes, int n_in,
                              void* d_out, int out_size, void* d_ws, size_t ws_size,
                              hipStream_t stream) {
  const float* x = (const float*)d_in[0];
  const float* G = (const float*)d_in[1];
  const float* H = (const float*)d_in[2];
  float* out = (float*)d_out;

  char* ws = (char*)d_ws;
  unsigned short* Mb = (unsigned short*)ws;                      // 8 MB  bf16 M[i][j]
  unsigned short* xb = (unsigned short*)(ws + (8u << 20));       // 16 MB bf16 x
  unsigned short* Dp = (unsigned short*)(ws + (24u << 20));      // 8 MB  bf16 diag-major

  const int cast_blocks = (kB * kN) / (256 * 8);                 // 4096
  prep_kernel<<<dim3(cast_blocks + kN), dim3(256), 0, stream>>>(x, G, H, xb, Dp);
  build_M_kernel<<<dim3(kN / 64, kN / 64), dim3(256), 0, stream>>>(Dp, Mb);
  zero_out_kernel<<<dim3((kB * kN) / (256 * 8)), dim3(256), 0, stream>>>((float4*)out);
  gemm_kernel<<<dim3(kN / 256, kB / 256, 2), dim3(512), 0, stream>>>(xb, Mb, out);
}